// Round 12
// baseline (115.074 us; speedup 1.0000x reference)
//
#include <hip/hip_runtime.h>
#include <math.h>

#define NV 16385
#define NEDGE 131072
#define NEG -1e30f
#define SCALE 2.8853900817779268f  // 2*log2(e): tanh(x) = 1 - 2/(exp2(SCALE*x)+1)

typedef __attribute__((ext_vector_type(8))) short short8;
typedef __attribute__((ext_vector_type(4))) float f32x4;

// Scratch as static device globals. g_gold/g_done reset by the final tail block
// each launch (.bss-zero on first launch) -> graph replays identical.
__device__ float g_part[4 * NEDGE];  // per-h-tile partial edge sums
__device__ float g_mats[32 * 64];    // 32 segment matrices (8x8, row-major)
__device__ float g_gold;             // gold-path sum
__device__ int g_done;               // segment-done counter

__device__ __forceinline__ unsigned short f2bf(float x) {
  union { float f; unsigned int u; } c; c.f = x;
  unsigned int u = c.u;
  unsigned int r = (u + 0x7fffu + ((u >> 16) & 1u)) >> 16;  // RNE
  return (unsigned short)r;
}

__device__ __forceinline__ float lse8(float x0, float x1, float x2, float x3,
                                      float x4, float x5, float x6, float x7) {
  float m = fmaxf(fmaxf(fmaxf(x0, x1), fmaxf(x2, x3)),
                  fmaxf(fmaxf(x4, x5), fmaxf(x6, x7)));
  float s = __expf(x0 - m) + __expf(x1 - m) + __expf(x2 - m) + __expf(x3 - m) +
            __expf(x4 - m) + __expf(x5 - m) + __expf(x6 - m) + __expf(x7 - m);
  return m + __logf(s);
}

// Full-wave 8x8 log-semiring matmul: lane l=(i*8+j) holds A[i][j], B[i][j];
// returns (A (X) B)[i][j] = lse_k(A[i][k] + B[k][j]).  A = later chunk.
__device__ __forceinline__ float comb8(float A, float B, int i8, int j) {
  float x0 = __shfl(A, i8 + 0) + __shfl(B, 0 + j);
  float x1 = __shfl(A, i8 + 1) + __shfl(B, 8 + j);
  float x2 = __shfl(A, i8 + 2) + __shfl(B, 16 + j);
  float x3 = __shfl(A, i8 + 3) + __shfl(B, 24 + j);
  float x4 = __shfl(A, i8 + 4) + __shfl(B, 32 + j);
  float x5 = __shfl(A, i8 + 5) + __shfl(B, 40 + j);
  float x6 = __shfl(A, i8 + 6) + __shfl(B, 48 + j);
  float x7 = __shfl(A, i8 + 7) + __shfl(B, 56 + j);
  return lse8(x0, x1, x2, x3, x4, x5, x6, x7);
}

// One edge-phase term: acc += w * rcp(exp2(x)+1)   (x pre-scaled by 2*log2e)
#define ETERM(x, w, acc)                                   \
  {                                                        \
    float e_ = __builtin_amdgcn_exp2f(x);                  \
    acc = fmaf(__builtin_amdgcn_rcpf(e_ + 1.f), (w), acc); \
  }

// Fused projection + edge kernel. Grid (4 h-tiles, 512 node-tiles of 32), 256 thr.
// vs R11: node-tile halved (32 nodes) -> 1 edge/thread, half the per-block
// critical path, 21.5 KB LDS -> 7 blocks/CU, 2048 blocks of scheduler slack.
__global__ __launch_bounds__(256, 7) void k12_fused(const float* __restrict__ emb,
                                                    const float* __restrict__ W1,
                                                    const float* __restrict__ b1,
                                                    const float* __restrict__ W2) {
  __shared__ __align__(16) unsigned short lds[11024];  // 21.5 KB
  unsigned short* Es = lds;               // [48][136] u16 emb tile (phase 1)
  float* CA  = (float*)lds;               // [48][68] f32 (aliases Es, phase 2)
  float* CB  = (float*)(lds + 6528);      // [32][68] f32 (byte 13056)
  float* W2s = (float*)(lds + 10880);     // [64] f32 (-2*W2)     (byte 21760)
  float* Wsum = (float*)(lds + 11008);    // [8] per-granule sum  (byte 22016)

  const int t = threadIdx.x;
  const int h0 = blockIdx.x << 6;
  const int i0 = blockIdx.y << 5;
  const int wv = t >> 6, lane = t & 63;
  const int l15 = lane & 15, quad = lane >> 4;
  const int colh = h0 + (wv << 4) + l15;  // this lane's W1 column / C column

  if (t < 64) W2s[t] = -2.f * W2[h0 + t];
  if (t < 8) {
    float s = 0.f;
#pragma unroll
    for (int jj = 0; jj < 8; ++jj) s += W2[h0 + (t << 3) + jj];
    Wsum[t] = s;
  }

  // Stage emb rows [i0-7, i0+41) x all 128 k -> bf16. 48 rows x 32 float4 = 1536.
#pragma unroll
  for (int it = 0; it < 6; ++it) {
    int idx = t + (it << 8);
    int row = idx >> 5;            // 0..47
    int k4 = (idx & 31) << 2;
    int v = i0 - 7 + row;
    float4 g = make_float4(0.f, 0.f, 0.f, 0.f);
    if (v >= 0 && v < NV) g = *(const float4*)&emb[v * 128 + k4];
    uint2 pk;
    pk.x = f2bf(g.x) | ((unsigned int)f2bf(g.y) << 16);
    pk.y = f2bf(g.z) | ((unsigned int)f2bf(g.w) << 16);
    *(uint2*)&Es[row * 136 + k4] = pk;
  }

  f32x4 accA[3], accB[2];
#pragma unroll
  for (int m = 0; m < 3; ++m) accA[m] = (f32x4){0.f, 0.f, 0.f, 0.f};
#pragma unroll
  for (int m = 0; m < 2; ++m) accB[m] = (f32x4){0.f, 0.f, 0.f, 0.f};

  // W1 fragments straight from global (L2-hot): frag kc -> k = kc*32 + quad*8 + i.
  short8 fA[4], fB[4];
#pragma unroll
  for (int kc = 0; kc < 4; ++kc) {
    const int kb = (kc << 5) + (quad << 3);
#pragma unroll
    for (int i = 0; i < 8; i += 2) {
      float a0 = W1[(kb + i) * 256 + colh];
      float a1 = W1[(kb + i + 1) * 256 + colh];
      float c0 = W1[(128 + kb + i) * 256 + colh];
      float c1 = W1[(128 + kb + i + 1) * 256 + colh];
      ((unsigned int*)&fA[kc])[i >> 1] = f2bf(a0) | ((unsigned int)f2bf(a1) << 16);
      ((unsigned int*)&fB[kc])[i >> 1] = f2bf(c0) | ((unsigned int)f2bf(c1) << 16);
    }
  }
  __syncthreads();

  // MFMA: A rows 0..47 (3 tiles; rows 39+ garbage -> unused C rows), B rows 8..39.
#pragma unroll
  for (int kc = 0; kc < 4; ++kc) {
    const int kbase = (kc << 5) + (quad << 3);
#pragma unroll
    for (int mf = 0; mf < 3; ++mf) {
      short8 a = *(const short8*)&Es[((mf << 4) + l15) * 136 + kbase];
      accA[mf] = __builtin_amdgcn_mfma_f32_16x16x32_bf16(a, fA[kc], accA[mf], 0, 0, 0);
    }
#pragma unroll
    for (int mf = 0; mf < 2; ++mf) {
      short8 a = *(const short8*)&Es[(8 + (mf << 4) + l15) * 136 + kbase];
      accB[mf] = __builtin_amdgcn_mfma_f32_16x16x32_bf16(a, fB[kc], accB[mf], 0, 0, 0);
    }
  }
  __syncthreads();  // all MFMA reads of Es done before aliasing C over it
  // Store C tiles fp32 (pre-scaled by 2*log2e; b1 folded into A).
  // C/D frag: row = quad*4+reg, col = lane&15.  Pitch 68.
  const int hcol = (wv << 4) + l15;
  const float b1s = b1[h0 + hcol];
#pragma unroll
  for (int mf = 0; mf < 3; ++mf) {
    int rb = (mf << 4) + (quad << 2);
#pragma unroll
    for (int rr = 0; rr < 4; ++rr)
      CA[(rb + rr) * 68 + hcol] = (accA[mf][rr] + b1s) * SCALE;
  }
#pragma unroll
  for (int mf = 0; mf < 2; ++mf) {
    int rb = (mf << 4) + (quad << 2);
#pragma unroll
    for (int rr = 0; rr < 4; ++rr)
      CB[(rb + rr) * 68 + hcol] = accB[mf][rr] * SCALE;
  }
  __syncthreads();
  // Edge phase: thread t owns ONE edge: q = t>>3 (node i0+1+q), k = t&7.
  const int k = t & 7;
  const int q = t >> 3;
  float ws_all = 0.f;
#pragma unroll
  for (int s = 0; s < 8; ++s) ws_all += Wsum[s];
  float pa0 = 0.f, pa1 = 0.f;
#pragma unroll
  for (int g = 0; g < 8; ++g) {
    const int s = (g + (k << 1)) & 7;  // granule rotation: conflict-uniform banks
    const float* wp = &W2s[s << 3];
    float4 w0 = *(const float4*)wp;
    float4 w1 = *(const float4*)(wp + 4);
    const float* ap = &CA[(7 + q - k) * 68 + (s << 3)];
    const float* bp = &CB[q * 68 + (s << 3)];
    float4 a0 = *(const float4*)ap, a1 = *(const float4*)(ap + 4);
    float4 b0 = *(const float4*)bp, b1v = *(const float4*)(bp + 4);
    ETERM(a0.x + b0.x, w0.x, pa0); ETERM(a0.y + b0.y, w0.y, pa0);
    ETERM(a0.z + b0.z, w0.z, pa0); ETERM(a0.w + b0.w, w0.w, pa0);
    ETERM(a1.x + b1v.x, w1.x, pa1); ETERM(a1.y + b1v.y, w1.y, pa1);
    ETERM(a1.z + b1v.z, w1.z, pa1); ETERM(a1.w + b1v.w, w1.w, pa1);
  }
  g_part[blockIdx.x * NEDGE + (blockIdx.y << 8) + t] = (pa0 + pa1) + ws_all;
}

// K_tail: 32 blocks x 256 (R8-proven). Block b: edges [b*4096,(b+1)*4096) ->
// softplus + gold + 8 chunk recurrences -> 1 segment matrix. Last block (ticket)
// combines 32 segment matrices and writes out. 33 device fences total.
__global__ __launch_bounds__(256) void k_tail(const float* __restrict__ b2,
                                              float* __restrict__ out) {
  __shared__ float wf[64][64];   // [step][chunk_local*8 + k]
  __shared__ float red[256];
  __shared__ float m8[8][64];    // 8 chunk matrices
  __shared__ float l2m[4][64];   // final-combine wave partials
  __shared__ int s_tick;
  const int t = threadIdx.x;
  const int b = blockIdx.x;
  const float b2v = b2[0];
  float gold = 0.f;
#pragma unroll
  for (int it = 0; it < 4; ++it) {
    const int e4 = t + (it << 8);
    const int gidx = (b << 10) + e4;
    float4 s0 = *(const float4*)&g_part[gidx << 2];
    float4 s1 = *(const float4*)&g_part[NEDGE + (gidx << 2)];
    float4 s2 = *(const float4*)&g_part[2 * NEDGE + (gidx << 2)];
    float4 s3 = *(const float4*)&g_part[3 * NEDGE + (gidx << 2)];
    float d0 = s0.x + s1.x + s2.x + s3.x + b2v;
    float d1 = s0.y + s1.y + s2.y + s3.y + b2v;
    float d2 = s0.z + s1.z + s2.z + s3.z + b2v;
    float d3 = s0.w + s1.w + s2.w + s3.w + b2v;
    d0 = fmaxf(d0, 0.f) + log1pf(__expf(-fabsf(d0)));
    d1 = fmaxf(d1, 0.f) + log1pf(__expf(-fabsf(d1)));
    d2 = fmaxf(d2, 0.f) + log1pf(__expf(-fabsf(d2)));
    d3 = fmaxf(d3, 0.f) + log1pf(__expf(-fabsf(d3)));
    const int q = e4 << 2;
    const int cl = q >> 9, r = q & 511;
    const int s = r >> 3, kk = r & 7;
    *(float4*)&wf[s][(cl << 3) + kk] = make_float4(d0, d1, d2, d3);
    if ((t & 1) == 0) gold += d0;  // k==0 edges (gold path)
  }
  red[t] = gold;
  __syncthreads();
  if (b == 0 && t == 0) {
    // node i = s+1 has valid preds kk <= s only: poison invalid d with +1e30
    for (int s = 0; s < 7; ++s)
      for (int kk = s + 1; kk < 8; ++kk) wf[s][kk] = 1e30f;
  }
  for (int o = 128; o > 0; o >>= 1) {
    __syncthreads();
    if (t < o) red[t] += red[t + o];
  }
  __syncthreads();
  if (t == 0) atomicAdd(&g_gold, red[0]);
  if (t < 64) {  // wave 0: 8 chunk recurrences (8 lanes each)
    const int g = t >> 3, j = t & 7;
    float P[8];
#pragma unroll
    for (int kk = 0; kk < 8; ++kk) P[kk] = (kk == j) ? 0.f : NEG;
    for (int s = 0; s < 64; ++s) {
      const float* wp = &wf[s][g << 3];
      float4 wa = *(const float4*)wp;
      float4 wb = *(const float4*)(wp + 4);
      float nv = lse8(P[0] - wa.x, P[1] - wa.y, P[2] - wa.z, P[3] - wa.w,
                      P[4] - wb.x, P[5] - wb.y, P[6] - wb.z, P[7] - wb.w);
#pragma unroll
      for (int kk = 7; kk > 0; --kk) P[kk] = P[kk - 1];
      P[0] = nv;
    }
#pragma unroll
    for (int kk = 0; kk < 8; ++kk) m8[g][(kk << 3) + j] = P[kk];  // row-major
    // Combine 8 chunk mats -> segment mat (in-wave, DS ops in-order).
    const int i8 = (t >> 3) << 3;
    float R = m8[0][t];
#pragma unroll
    for (int g2 = 1; g2 < 8; ++g2) R = comb8(m8[g2][t], R, i8, j);
    g_mats[(b << 6) + t] = R;
  }
  __threadfence();
  __syncthreads();
  if (t == 0) s_tick = atomicAdd(&g_done, 1);
  __syncthreads();
  if (s_tick != 31) return;
  __threadfence();  // acquire: all 32 segment mats + gold adds visible

  // Final combine of 32 segment matrices. Wave w: segs 8w..8w+7.
  {
    const int l = t & 63, w = t >> 6;
    const int i8 = (l >> 3) << 3, j = l & 7;
    float G = g_mats[((w << 3) << 6) + l];
#pragma unroll
    for (int s2 = 1; s2 < 8; ++s2)
      G = comb8(g_mats[(((w << 3) + s2) << 6) + l], G, i8, j);
    l2m[w][l] = G;
    __syncthreads();
    if (t < 64) {
      float G2 = l2m[0][t];
#pragma unroll
      for (int w2 = 1; w2 < 4; ++w2) G2 = comb8(l2m[w2][t], G2, i8, j);
      if (t == 0) {
        out[0] = g_gold + G2;  // gold + (prod)[0][0]
        g_gold = 0.f;          // reset for next launch / graph replay
        g_done = 0;
      }
    }
  }
}

extern "C" void kernel_launch(void* const* d_in, const int* in_sizes, int n_in,
                              void* d_out, int out_size, void* d_ws, size_t ws_size,
                              hipStream_t stream) {
  const float* emb = (const float*)d_in[0];
  const float* W1 = (const float*)d_in[1];
  const float* b1 = (const float*)d_in[2];
  const float* W2 = (const float*)d_in[3];
  const float* b2 = (const float*)d_in[4];
  float* out = (float*)d_out;
  hipLaunchKernelGGL(k12_fused, dim3(4, 512), dim3(256), 0, stream, emb, W1, b1, W2);
  hipLaunchKernelGGL(k_tail, dim3(32), dim3(256), 0, stream, b2, out);
}

// Round 13
// 111.428 us; speedup vs baseline: 1.0327x; 1.0327x over previous
//
#include <hip/hip_runtime.h>
#include <math.h>

#define NV 16385
#define NEDGE 131072
#define NEG -1e30f
#define SCALE 2.8853900817779268f  // 2*log2(e): tanh(x) = 1 - 2/(exp2(SCALE*x)+1)

typedef __attribute__((ext_vector_type(8))) short short8;
typedef __attribute__((ext_vector_type(4))) float f32x4;

// Scratch as static device globals. g_gold/g_done reset by the final tail block
// each launch (.bss-zero on first launch) -> graph replays identical.
__device__ float g_part[4 * NEDGE];  // per-h-tile partial edge sums
__device__ float g_mats[32 * 64];    // 32 segment matrices (8x8, row-major)
__device__ float g_gold;             // gold-path sum
__device__ int g_done;               // segment-done counter

__device__ __forceinline__ unsigned short f2bf(float x) {
  union { float f; unsigned int u; } c; c.f = x;
  unsigned int u = c.u;
  unsigned int r = (u + 0x7fffu + ((u >> 16) & 1u)) >> 16;  // RNE
  return (unsigned short)r;
}

__device__ __forceinline__ float lse8(float x0, float x1, float x2, float x3,
                                      float x4, float x5, float x6, float x7) {
  float m = fmaxf(fmaxf(fmaxf(x0, x1), fmaxf(x2, x3)),
                  fmaxf(fmaxf(x4, x5), fmaxf(x6, x7)));
  float s = __expf(x0 - m) + __expf(x1 - m) + __expf(x2 - m) + __expf(x3 - m) +
            __expf(x4 - m) + __expf(x5 - m) + __expf(x6 - m) + __expf(x7 - m);
  return m + __logf(s);
}

// Full-wave 8x8 log-semiring matmul: lane l=(i*8+j) holds A[i][j], B[i][j];
// returns (A (X) B)[i][j] = lse_k(A[i][k] + B[k][j]).  A = later chunk.
__device__ __forceinline__ float comb8(float A, float B, int i8, int j) {
  float x0 = __shfl(A, i8 + 0) + __shfl(B, 0 + j);
  float x1 = __shfl(A, i8 + 1) + __shfl(B, 8 + j);
  float x2 = __shfl(A, i8 + 2) + __shfl(B, 16 + j);
  float x3 = __shfl(A, i8 + 3) + __shfl(B, 24 + j);
  float x4 = __shfl(A, i8 + 4) + __shfl(B, 32 + j);
  float x5 = __shfl(A, i8 + 5) + __shfl(B, 40 + j);
  float x6 = __shfl(A, i8 + 6) + __shfl(B, 48 + j);
  float x7 = __shfl(A, i8 + 7) + __shfl(B, 56 + j);
  return lse8(x0, x1, x2, x3, x4, x5, x6, x7);
}

// One edge-phase term with FACTORED exponential: ea/eb are exp2-domain values
// (ea*eb = exp2(2log2e*(A+B+b1))).  acc += w * rcp(ea*eb + 1); only 1 trans op.
#define ETERM(ea, eb, w, acc)                              \
  {                                                        \
    float e_ = (ea) * (eb);                                \
    acc = fmaf(__builtin_amdgcn_rcpf(e_ + 1.f), (w), acc); \
  }

// Fused projection + edge kernel. Grid (4 h-tiles, 256 node-tiles of 64), 256 thr.
// R11 structure; C tiles stored as EA=exp2(SCALE*(A+b1)), EB=exp2(SCALE*B) so the
// edge phase needs only rcp (trans-pipe halved: exp2 count 33.5M -> 5.2M).
__global__ __launch_bounds__(256, 4) void k12_fused(const float* __restrict__ emb,
                                                    const float* __restrict__ W1,
                                                    const float* __restrict__ b1,
                                                    const float* __restrict__ W2) {
  __shared__ __align__(16) unsigned short lds[19728];  // 38.5 KB
  unsigned short* Es = lds;               // [80][136] u16 emb tile (phase 1)
  float* CA  = (float*)lds;               // [80][68] f32 EA (aliases Es, phase 2)
  float* CB  = (float*)(lds + 10880);     // [64][68] f32 EB (byte 21760)
  float* W2s = (float*)(lds + 19584);     // [64] f32 (-2*W2)       (byte 39168)
  float* Wsum = (float*)(lds + 19712);    // [8] per-granule sum    (byte 39424)

  const int t = threadIdx.x;
  const int h0 = blockIdx.x << 6;
  const int i0 = blockIdx.y << 6;
  const int wv = t >> 6, lane = t & 63;
  const int l15 = lane & 15, quad = lane >> 4;
  const int colh = h0 + (wv << 4) + l15;  // this lane's W1 column / C column

  if (t < 64) W2s[t] = -2.f * W2[h0 + t];
  if (t < 8) {
    float s = 0.f;
#pragma unroll
    for (int jj = 0; jj < 8; ++jj) s += W2[h0 + (t << 3) + jj];
    Wsum[t] = s;
  }

  // Stage emb rows [i0-7, i0+73) x all 128 k -> bf16. 80 rows x 32 float4 = 2560.
#pragma unroll
  for (int it = 0; it < 10; ++it) {
    int idx = t + (it << 8);
    int row = idx >> 5;
    int k4 = (idx & 31) << 2;
    int v = i0 - 7 + row;
    float4 g = make_float4(0.f, 0.f, 0.f, 0.f);
    if (v >= 0 && v < NV) g = *(const float4*)&emb[v * 128 + k4];
    uint2 pk;
    pk.x = f2bf(g.x) | ((unsigned int)f2bf(g.y) << 16);
    pk.y = f2bf(g.z) | ((unsigned int)f2bf(g.w) << 16);
    *(uint2*)&Es[row * 136 + k4] = pk;
  }

  f32x4 accA[5], accB[4];
#pragma unroll
  for (int m = 0; m < 5; ++m) accA[m] = (f32x4){0.f, 0.f, 0.f, 0.f};
#pragma unroll
  for (int m = 0; m < 4; ++m) accB[m] = (f32x4){0.f, 0.f, 0.f, 0.f};

  // W1 fragments straight from global (L2-hot): frag kc -> k = kc*32 + quad*8 + i.
  short8 fA[4], fB[4];
#pragma unroll
  for (int kc = 0; kc < 4; ++kc) {
    const int kb = (kc << 5) + (quad << 3);
#pragma unroll
    for (int i = 0; i < 8; i += 2) {
      float a0 = W1[(kb + i) * 256 + colh];
      float a1 = W1[(kb + i + 1) * 256 + colh];
      float c0 = W1[(128 + kb + i) * 256 + colh];
      float c1 = W1[(128 + kb + i + 1) * 256 + colh];
      ((unsigned int*)&fA[kc])[i >> 1] = f2bf(a0) | ((unsigned int)f2bf(a1) << 16);
      ((unsigned int*)&fB[kc])[i >> 1] = f2bf(c0) | ((unsigned int)f2bf(c1) << 16);
    }
  }
  __syncthreads();

#pragma unroll
  for (int kc = 0; kc < 4; ++kc) {
    const int kbase = (kc << 5) + (quad << 3);
#pragma unroll
    for (int mf = 0; mf < 5; ++mf) {
      short8 a = *(const short8*)&Es[((mf << 4) + l15) * 136 + kbase];
      accA[mf] = __builtin_amdgcn_mfma_f32_16x16x32_bf16(a, fA[kc], accA[mf], 0, 0, 0);
    }
#pragma unroll
    for (int mf = 0; mf < 4; ++mf) {
      short8 a = *(const short8*)&Es[(8 + (mf << 4) + l15) * 136 + kbase];
      accB[mf] = __builtin_amdgcn_mfma_f32_16x16x32_bf16(a, fB[kc], accB[mf], 0, 0, 0);
    }
  }
  __syncthreads();  // all MFMA reads of Es done before aliasing C over it
  // Store C tiles in exp2 domain: EA = exp2(SCALE*(A+b1)), EB = exp2(SCALE*B).
  // C/D frag: row = quad*4+reg, col = lane&15.  Pitch 68: 2-way conflicts (free).
  const int hcol = (wv << 4) + l15;
  const float b1s = b1[h0 + hcol];
#pragma unroll
  for (int mf = 0; mf < 5; ++mf) {
    int rb = (mf << 4) + (quad << 2);
#pragma unroll
    for (int rr = 0; rr < 4; ++rr)
      CA[(rb + rr) * 68 + hcol] =
          __builtin_amdgcn_exp2f((accA[mf][rr] + b1s) * SCALE);
  }
#pragma unroll
  for (int mf = 0; mf < 4; ++mf) {
    int rb = (mf << 4) + (quad << 2);
#pragma unroll
    for (int rr = 0; rr < 4; ++rr)
      CB[(rb + rr) * 68 + hcol] = __builtin_amdgcn_exp2f(accB[mf][rr] * SCALE);
  }
  __syncthreads();
  // Edge phase: thread t -> k = t&7, qb = t>>3; edges q = qb, qb+32.
  // 4 independent accumulators; Wsum folded once at the end.
  const int k = t & 7;
  const int qb = t >> 3;
  float ws_all = 0.f;
#pragma unroll
  for (int s = 0; s < 8; ++s) ws_all += Wsum[s];
  float pa0 = 0.f, pa1 = 0.f, pb0 = 0.f, pb1 = 0.f;
#pragma unroll
  for (int g = 0; g < 8; ++g) {
    const int s = (g + (k << 1)) & 7;  // granule rotation: conflict-uniform banks
    const float* wp = &W2s[s << 3];
    float4 w0 = *(const float4*)wp;
    float4 w1 = *(const float4*)(wp + 4);
    {
      const float* ap = &CA[(7 + qb - k) * 68 + (s << 3)];
      const float* bp = &CB[qb * 68 + (s << 3)];
      float4 a0 = *(const float4*)ap, a1 = *(const float4*)(ap + 4);
      float4 b0 = *(const float4*)bp, b1v = *(const float4*)(bp + 4);
      ETERM(a0.x, b0.x, w0.x, pa0); ETERM(a0.y, b0.y, w0.y, pa0);
      ETERM(a0.z, b0.z, w0.z, pa0); ETERM(a0.w, b0.w, w0.w, pa0);
      ETERM(a1.x, b1v.x, w1.x, pa1); ETERM(a1.y, b1v.y, w1.y, pa1);
      ETERM(a1.z, b1v.z, w1.z, pa1); ETERM(a1.w, b1v.w, w1.w, pa1);
    }
    {
      const int q = qb + 32;
      const float* ap = &CA[(7 + q - k) * 68 + (s << 3)];
      const float* bp = &CB[q * 68 + (s << 3)];
      float4 a0 = *(const float4*)ap, a1 = *(const float4*)(ap + 4);
      float4 b0 = *(const float4*)bp, b1v = *(const float4*)(bp + 4);
      ETERM(a0.x, b0.x, w0.x, pb0); ETERM(a0.y, b0.y, w0.y, pb0);
      ETERM(a0.z, b0.z, w0.z, pb0); ETERM(a0.w, b0.w, w0.w, pb0);
      ETERM(a1.x, b1v.x, w1.x, pb1); ETERM(a1.y, b1v.y, w1.y, pb1);
      ETERM(a1.z, b1v.z, w1.z, pb1); ETERM(a1.w, b1v.w, w1.w, pb1);
    }
  }
  const int ebase = blockIdx.x * NEDGE + (blockIdx.y << 9) + t;
  g_part[ebase] = (pa0 + pa1) + ws_all;
  g_part[ebase + 256] = (pb0 + pb1) + ws_all;
}

// K_tail: 32 blocks x 256 (R8-proven). Block b: edges [b*4096,(b+1)*4096) ->
// softplus + gold + 8 chunk recurrences -> 1 segment matrix. Last block (ticket)
// combines 32 segment matrices and writes out. 33 device fences total.
__global__ __launch_bounds__(256) void k_tail(const float* __restrict__ b2,
                                              float* __restrict__ out) {
  __shared__ float wf[64][64];   // [step][chunk_local*8 + k]
  __shared__ float red[256];
  __shared__ float m8[8][64];    // 8 chunk matrices
  __shared__ float l2m[4][64];   // final-combine wave partials
  __shared__ int s_tick;
  const int t = threadIdx.x;
  const int b = blockIdx.x;
  const float b2v = b2[0];
  float gold = 0.f;
#pragma unroll
  for (int it = 0; it < 4; ++it) {
    const int e4 = t + (it << 8);
    const int gidx = (b << 10) + e4;
    float4 s0 = *(const float4*)&g_part[gidx << 2];
    float4 s1 = *(const float4*)&g_part[NEDGE + (gidx << 2)];
    float4 s2 = *(const float4*)&g_part[2 * NEDGE + (gidx << 2)];
    float4 s3 = *(const float4*)&g_part[3 * NEDGE + (gidx << 2)];
    float d0 = s0.x + s1.x + s2.x + s3.x + b2v;
    float d1 = s0.y + s1.y + s2.y + s3.y + b2v;
    float d2 = s0.z + s1.z + s2.z + s3.z + b2v;
    float d3 = s0.w + s1.w + s2.w + s3.w + b2v;
    d0 = fmaxf(d0, 0.f) + log1pf(__expf(-fabsf(d0)));
    d1 = fmaxf(d1, 0.f) + log1pf(__expf(-fabsf(d1)));
    d2 = fmaxf(d2, 0.f) + log1pf(__expf(-fabsf(d2)));
    d3 = fmaxf(d3, 0.f) + log1pf(__expf(-fabsf(d3)));
    const int q = e4 << 2;
    const int cl = q >> 9, r = q & 511;
    const int s = r >> 3, kk = r & 7;
    *(float4*)&wf[s][(cl << 3) + kk] = make_float4(d0, d1, d2, d3);
    if ((t & 1) == 0) gold += d0;  // k==0 edges (gold path)
  }
  red[t] = gold;
  __syncthreads();
  if (b == 0 && t == 0) {
    // node i = s+1 has valid preds kk <= s only: poison invalid d with +1e30
    for (int s = 0; s < 7; ++s)
      for (int kk = s + 1; kk < 8; ++kk) wf[s][kk] = 1e30f;
  }
  for (int o = 128; o > 0; o >>= 1) {
    __syncthreads();
    if (t < o) red[t] += red[t + o];
  }
  __syncthreads();
  if (t == 0) atomicAdd(&g_gold, red[0]);
  if (t < 64) {  // wave 0: 8 chunk recurrences (8 lanes each)
    const int g = t >> 3, j = t & 7;
    float P[8];
#pragma unroll
    for (int kk = 0; kk < 8; ++kk) P[kk] = (kk == j) ? 0.f : NEG;
    for (int s = 0; s < 64; ++s) {
      const float* wp = &wf[s][g << 3];
      float4 wa = *(const float4*)wp;
      float4 wb = *(const float4*)(wp + 4);
      float nv = lse8(P[0] - wa.x, P[1] - wa.y, P[2] - wa.z, P[3] - wa.w,
                      P[4] - wb.x, P[5] - wb.y, P[6] - wb.z, P[7] - wb.w);
#pragma unroll
      for (int kk = 7; kk > 0; --kk) P[kk] = P[kk - 1];
      P[0] = nv;
    }
#pragma unroll
    for (int kk = 0; kk < 8; ++kk) m8[g][(kk << 3) + j] = P[kk];  // row-major
    // Combine 8 chunk mats -> segment mat (in-wave, DS ops in-order).
    const int i8 = (t >> 3) << 3;
    float R = m8[0][t];
#pragma unroll
    for (int g2 = 1; g2 < 8; ++g2) R = comb8(m8[g2][t], R, i8, j);
    g_mats[(b << 6) + t] = R;
  }
  __threadfence();
  __syncthreads();
  if (t == 0) s_tick = atomicAdd(&g_done, 1);
  __syncthreads();
  if (s_tick != 31) return;
  __threadfence();  // acquire: all 32 segment mats + gold adds visible

  // Final combine of 32 segment matrices. Wave w: segs 8w..8w+7.
  {
    const int l = t & 63, w = t >> 6;
    const int i8 = (l >> 3) << 3, j = l & 7;
    float G = g_mats[((w << 3) << 6) + l];
#pragma unroll
    for (int s2 = 1; s2 < 8; ++s2)
      G = comb8(g_mats[(((w << 3) + s2) << 6) + l], G, i8, j);
    l2m[w][l] = G;
    __syncthreads();
    if (t < 64) {
      float G2 = l2m[0][t];
#pragma unroll
      for (int w2 = 1; w2 < 4; ++w2) G2 = comb8(l2m[w2][t], G2, i8, j);
      if (t == 0) {
        out[0] = g_gold + G2;  // gold + (prod)[0][0]
        g_gold = 0.f;          // reset for next launch / graph replay
        g_done = 0;
      }
    }
  }
}

extern "C" void kernel_launch(void* const* d_in, const int* in_sizes, int n_in,
                              void* d_out, int out_size, void* d_ws, size_t ws_size,
                              hipStream_t stream) {
  const float* emb = (const float*)d_in[0];
  const float* W1 = (const float*)d_in[1];
  const float* b1 = (const float*)d_in[2];
  const float* W2 = (const float*)d_in[3];
  const float* b2 = (const float*)d_in[4];
  float* out = (float*)d_out;
  hipLaunchKernelGGL(k12_fused, dim3(4, 256), dim3(256), 0, stream, emb, W1, b1, W2);
  hipLaunchKernelGGL(k_tail, dim3(32), dim3(256), 0, stream, b2, out);
}

// Round 14
// 109.865 us; speedup vs baseline: 1.0474x; 1.0142x over previous
//
#include <hip/hip_runtime.h>
#include <math.h>

#define NV 16385
#define NEDGE 131072
#define NEG -1e30f
#define SCALE 2.8853900817779268f  // 2*log2(e): tanh(x) = 1 - 2/(exp2(SCALE*x)+1)

typedef __attribute__((ext_vector_type(8))) short short8;
typedef __attribute__((ext_vector_type(4))) float f32x4;

// Scratch as static device globals. g_gold reset by k_tail2 each launch
// (.bss-zero on first launch) -> graph replays identical.
__device__ float g_part[4 * NEDGE];  // per-h-tile partial edge sums
__device__ float g_mats[32 * 64];    // 32 segment matrices (8x8, row-major)
__device__ float g_gold;             // gold-path sum

__device__ __forceinline__ unsigned short f2bf(float x) {
  union { float f; unsigned int u; } c; c.f = x;
  unsigned int u = c.u;
  unsigned int r = (u + 0x7fffu + ((u >> 16) & 1u)) >> 16;  // RNE
  return (unsigned short)r;
}

__device__ __forceinline__ float lse8(float x0, float x1, float x2, float x3,
                                      float x4, float x5, float x6, float x7) {
  float m = fmaxf(fmaxf(fmaxf(x0, x1), fmaxf(x2, x3)),
                  fmaxf(fmaxf(x4, x5), fmaxf(x6, x7)));
  float s = __expf(x0 - m) + __expf(x1 - m) + __expf(x2 - m) + __expf(x3 - m) +
            __expf(x4 - m) + __expf(x5 - m) + __expf(x6 - m) + __expf(x7 - m);
  return m + __logf(s);
}

// Full-wave 8x8 log-semiring matmul: lane l=(i*8+j) holds A[i][j], B[i][j];
// returns (A (X) B)[i][j] = lse_k(A[i][k] + B[k][j]).  A = later chunk.
__device__ __forceinline__ float comb8(float A, float B, int i8, int j) {
  float x0 = __shfl(A, i8 + 0) + __shfl(B, 0 + j);
  float x1 = __shfl(A, i8 + 1) + __shfl(B, 8 + j);
  float x2 = __shfl(A, i8 + 2) + __shfl(B, 16 + j);
  float x3 = __shfl(A, i8 + 3) + __shfl(B, 24 + j);
  float x4 = __shfl(A, i8 + 4) + __shfl(B, 32 + j);
  float x5 = __shfl(A, i8 + 5) + __shfl(B, 40 + j);
  float x6 = __shfl(A, i8 + 6) + __shfl(B, 48 + j);
  float x7 = __shfl(A, i8 + 7) + __shfl(B, 56 + j);
  return lse8(x0, x1, x2, x3, x4, x5, x6, x7);
}

// One edge-phase term with FACTORED exponential: ea/eb are exp2-domain values
// (ea*eb = exp2(2log2e*(A+B+b1))).  acc += w * rcp(ea*eb + 1); only 1 trans op.
#define ETERM(ea, eb, w, acc)                              \
  {                                                        \
    float e_ = (ea) * (eb);                                \
    acc = fmaf(__builtin_amdgcn_rcpf(e_ + 1.f), (w), acc); \
  }

// Fused projection + edge kernel (R13-proven). Grid (4 h-tiles, 256 node-tiles
// of 64), 256 thr. C tiles stored in exp2 domain so edge phase needs only rcp.
__global__ __launch_bounds__(256, 4) void k12_fused(const float* __restrict__ emb,
                                                    const float* __restrict__ W1,
                                                    const float* __restrict__ b1,
                                                    const float* __restrict__ W2) {
  __shared__ __align__(16) unsigned short lds[19728];  // 38.5 KB
  unsigned short* Es = lds;               // [80][136] u16 emb tile (phase 1)
  float* CA  = (float*)lds;               // [80][68] f32 EA (aliases Es, phase 2)
  float* CB  = (float*)(lds + 10880);     // [64][68] f32 EB (byte 21760)
  float* W2s = (float*)(lds + 19584);     // [64] f32 (-2*W2)       (byte 39168)
  float* Wsum = (float*)(lds + 19712);    // [8] per-granule sum    (byte 39424)

  const int t = threadIdx.x;
  const int h0 = blockIdx.x << 6;
  const int i0 = blockIdx.y << 6;
  const int wv = t >> 6, lane = t & 63;
  const int l15 = lane & 15, quad = lane >> 4;
  const int colh = h0 + (wv << 4) + l15;  // this lane's W1 column / C column

  if (t < 64) W2s[t] = -2.f * W2[h0 + t];
  if (t < 8) {
    float s = 0.f;
#pragma unroll
    for (int jj = 0; jj < 8; ++jj) s += W2[h0 + (t << 3) + jj];
    Wsum[t] = s;
  }

  // Stage emb rows [i0-7, i0+73) x all 128 k -> bf16. 80 rows x 32 float4 = 2560.
#pragma unroll
  for (int it = 0; it < 10; ++it) {
    int idx = t + (it << 8);
    int row = idx >> 5;
    int k4 = (idx & 31) << 2;
    int v = i0 - 7 + row;
    float4 g = make_float4(0.f, 0.f, 0.f, 0.f);
    if (v >= 0 && v < NV) g = *(const float4*)&emb[v * 128 + k4];
    uint2 pk;
    pk.x = f2bf(g.x) | ((unsigned int)f2bf(g.y) << 16);
    pk.y = f2bf(g.z) | ((unsigned int)f2bf(g.w) << 16);
    *(uint2*)&Es[row * 136 + k4] = pk;
  }

  f32x4 accA[5], accB[4];
#pragma unroll
  for (int m = 0; m < 5; ++m) accA[m] = (f32x4){0.f, 0.f, 0.f, 0.f};
#pragma unroll
  for (int m = 0; m < 4; ++m) accB[m] = (f32x4){0.f, 0.f, 0.f, 0.f};

  // W1 fragments straight from global (L2-hot): frag kc -> k = kc*32 + quad*8 + i.
  short8 fA[4], fB[4];
#pragma unroll
  for (int kc = 0; kc < 4; ++kc) {
    const int kb = (kc << 5) + (quad << 3);
#pragma unroll
    for (int i = 0; i < 8; i += 2) {
      float a0 = W1[(kb + i) * 256 + colh];
      float a1 = W1[(kb + i + 1) * 256 + colh];
      float c0 = W1[(128 + kb + i) * 256 + colh];
      float c1 = W1[(128 + kb + i + 1) * 256 + colh];
      ((unsigned int*)&fA[kc])[i >> 1] = f2bf(a0) | ((unsigned int)f2bf(a1) << 16);
      ((unsigned int*)&fB[kc])[i >> 1] = f2bf(c0) | ((unsigned int)f2bf(c1) << 16);
    }
  }
  __syncthreads();

#pragma unroll
  for (int kc = 0; kc < 4; ++kc) {
    const int kbase = (kc << 5) + (quad << 3);
#pragma unroll
    for (int mf = 0; mf < 5; ++mf) {
      short8 a = *(const short8*)&Es[((mf << 4) + l15) * 136 + kbase];
      accA[mf] = __builtin_amdgcn_mfma_f32_16x16x32_bf16(a, fA[kc], accA[mf], 0, 0, 0);
    }
#pragma unroll
    for (int mf = 0; mf < 4; ++mf) {
      short8 a = *(const short8*)&Es[(8 + (mf << 4) + l15) * 136 + kbase];
      accB[mf] = __builtin_amdgcn_mfma_f32_16x16x32_bf16(a, fB[kc], accB[mf], 0, 0, 0);
    }
  }
  __syncthreads();  // all MFMA reads of Es done before aliasing C over it
  // Store C tiles in exp2 domain: EA = exp2(SCALE*(A+b1)), EB = exp2(SCALE*B).
  // C/D frag: row = quad*4+reg, col = lane&15.  Pitch 68: 2-way conflicts (free).
  const int hcol = (wv << 4) + l15;
  const float b1s = b1[h0 + hcol];
#pragma unroll
  for (int mf = 0; mf < 5; ++mf) {
    int rb = (mf << 4) + (quad << 2);
#pragma unroll
    for (int rr = 0; rr < 4; ++rr)
      CA[(rb + rr) * 68 + hcol] =
          __builtin_amdgcn_exp2f((accA[mf][rr] + b1s) * SCALE);
  }
#pragma unroll
  for (int mf = 0; mf < 4; ++mf) {
    int rb = (mf << 4) + (quad << 2);
#pragma unroll
    for (int rr = 0; rr < 4; ++rr)
      CB[(rb + rr) * 68 + hcol] = __builtin_amdgcn_exp2f(accB[mf][rr] * SCALE);
  }
  __syncthreads();
  // Edge phase: thread t -> k = t&7, qb = t>>3; edges q = qb, qb+32.
  const int k = t & 7;
  const int qb = t >> 3;
  float ws_all = 0.f;
#pragma unroll
  for (int s = 0; s < 8; ++s) ws_all += Wsum[s];
  float pa0 = 0.f, pa1 = 0.f, pb0 = 0.f, pb1 = 0.f;
#pragma unroll
  for (int g = 0; g < 8; ++g) {
    const int s = (g + (k << 1)) & 7;  // granule rotation: conflict-uniform banks
    const float* wp = &W2s[s << 3];
    float4 w0 = *(const float4*)wp;
    float4 w1 = *(const float4*)(wp + 4);
    {
      const float* ap = &CA[(7 + qb - k) * 68 + (s << 3)];
      const float* bp = &CB[qb * 68 + (s << 3)];
      float4 a0 = *(const float4*)ap, a1 = *(const float4*)(ap + 4);
      float4 b0 = *(const float4*)bp, b1v = *(const float4*)(bp + 4);
      ETERM(a0.x, b0.x, w0.x, pa0); ETERM(a0.y, b0.y, w0.y, pa0);
      ETERM(a0.z, b0.z, w0.z, pa0); ETERM(a0.w, b0.w, w0.w, pa0);
      ETERM(a1.x, b1v.x, w1.x, pa1); ETERM(a1.y, b1v.y, w1.y, pa1);
      ETERM(a1.z, b1v.z, w1.z, pa1); ETERM(a1.w, b1v.w, w1.w, pa1);
    }
    {
      const int q = qb + 32;
      const float* ap = &CA[(7 + q - k) * 68 + (s << 3)];
      const float* bp = &CB[q * 68 + (s << 3)];
      float4 a0 = *(const float4*)ap, a1 = *(const float4*)(ap + 4);
      float4 b0 = *(const float4*)bp, b1v = *(const float4*)(bp + 4);
      ETERM(a0.x, b0.x, w0.x, pb0); ETERM(a0.y, b0.y, w0.y, pb0);
      ETERM(a0.z, b0.z, w0.z, pb0); ETERM(a0.w, b0.w, w0.w, pb0);
      ETERM(a1.x, b1v.x, w1.x, pb1); ETERM(a1.y, b1v.y, w1.y, pb1);
      ETERM(a1.z, b1v.z, w1.z, pb1); ETERM(a1.w, b1v.w, w1.w, pb1);
    }
  }
  const int ebase = blockIdx.x * NEDGE + (blockIdx.y << 9) + t;
  g_part[ebase] = (pa0 + pa1) + ws_all;
  g_part[ebase + 256] = (pb0 + pb1) + ws_all;
}

// K_tail1: 32 blocks x 256. Block b: edges [b*4096,(b+1)*4096) -> softplus +
// gold (wave-shuffle + atomicAdd) + 8 chunk recurrences -> 1 segment matrix.
// NO fences, NO tickets — the kernel boundary publishes g_mats/g_gold.
__global__ __launch_bounds__(256) void k_tail1(const float* __restrict__ b2) {
  __shared__ float wf[64][64];   // [step][chunk_local*8 + k]
  __shared__ float m8[8][64];    // 8 chunk matrices
  const int t = threadIdx.x;
  const int b = blockIdx.x;
  const float b2v = b2[0];
  float gold = 0.f;
#pragma unroll
  for (int it = 0; it < 4; ++it) {
    const int e4 = t + (it << 8);
    const int gidx = (b << 10) + e4;
    float4 s0 = *(const float4*)&g_part[gidx << 2];
    float4 s1 = *(const float4*)&g_part[NEDGE + (gidx << 2)];
    float4 s2 = *(const float4*)&g_part[2 * NEDGE + (gidx << 2)];
    float4 s3 = *(const float4*)&g_part[3 * NEDGE + (gidx << 2)];
    float d0 = s0.x + s1.x + s2.x + s3.x + b2v;
    float d1 = s0.y + s1.y + s2.y + s3.y + b2v;
    float d2 = s0.z + s1.z + s2.z + s3.z + b2v;
    float d3 = s0.w + s1.w + s2.w + s3.w + b2v;
    d0 = fmaxf(d0, 0.f) + log1pf(__expf(-fabsf(d0)));
    d1 = fmaxf(d1, 0.f) + log1pf(__expf(-fabsf(d1)));
    d2 = fmaxf(d2, 0.f) + log1pf(__expf(-fabsf(d2)));
    d3 = fmaxf(d3, 0.f) + log1pf(__expf(-fabsf(d3)));
    const int q = e4 << 2;
    const int cl = q >> 9, r = q & 511;
    const int s = r >> 3, kk = r & 7;
    *(float4*)&wf[s][(cl << 3) + kk] = make_float4(d0, d1, d2, d3);
    if ((t & 1) == 0) gold += d0;  // k==0 edges (gold path)
  }
  // Gold: butterfly within wave, one atomic per wave (4/block, 128 total).
#pragma unroll
  for (int off = 32; off > 0; off >>= 1) gold += __shfl_xor(gold, off, 64);
  if ((t & 63) == 0) atomicAdd(&g_gold, gold);
  __syncthreads();
  if (b == 0 && t == 0) {
    // node i = s+1 has valid preds kk <= s only: poison invalid d with +1e30
    for (int s = 0; s < 7; ++s)
      for (int kk = s + 1; kk < 8; ++kk) wf[s][kk] = 1e30f;
  }
  __syncthreads();
  if (t < 64) {  // wave 0: 8 chunk recurrences (8 lanes each)
    const int g = t >> 3, j = t & 7;
    float P[8];
#pragma unroll
    for (int kk = 0; kk < 8; ++kk) P[kk] = (kk == j) ? 0.f : NEG;
    for (int s = 0; s < 64; ++s) {
      const float* wp = &wf[s][g << 3];
      float4 wa = *(const float4*)wp;
      float4 wb = *(const float4*)(wp + 4);
      float nv = lse8(P[0] - wa.x, P[1] - wa.y, P[2] - wa.z, P[3] - wa.w,
                      P[4] - wb.x, P[5] - wb.y, P[6] - wb.z, P[7] - wb.w);
#pragma unroll
      for (int kk = 7; kk > 0; --kk) P[kk] = P[kk - 1];
      P[0] = nv;
    }
#pragma unroll
    for (int kk = 0; kk < 8; ++kk) m8[g][(kk << 3) + j] = P[kk];  // row-major
    // Combine 8 chunk mats -> segment mat (in-wave, DS ops in-order).
    const int i8 = (t >> 3) << 3;
    float R = m8[0][t];
#pragma unroll
    for (int g2 = 1; g2 < 8; ++g2) R = comb8(m8[g2][t], R, i8, j);
    g_mats[(b << 6) + t] = R;
  }
}

// K_tail2: 1 block x 256. Final combine of 32 segment matrices + out + reset.
__global__ __launch_bounds__(256) void k_tail2(float* __restrict__ out) {
  __shared__ float l2m[4][64];
  const int t = threadIdx.x;
  const int l = t & 63, w = t >> 6;
  const int i8 = (l >> 3) << 3, j = l & 7;
  float G = g_mats[((w << 3) << 6) + l];
#pragma unroll
  for (int s2 = 1; s2 < 8; ++s2)
    G = comb8(g_mats[(((w << 3) + s2) << 6) + l], G, i8, j);
  l2m[w][l] = G;
  __syncthreads();
  if (t < 64) {
    float G2 = l2m[0][t];
#pragma unroll
    for (int w2 = 1; w2 < 4; ++w2) G2 = comb8(l2m[w2][t], G2, i8, j);
    if (t == 0) {
      out[0] = g_gold + G2;  // gold + (prod)[0][0]
      g_gold = 0.f;          // reset for next launch / graph replay
    }
  }
}

extern "C" void kernel_launch(void* const* d_in, const int* in_sizes, int n_in,
                              void* d_out, int out_size, void* d_ws, size_t ws_size,
                              hipStream_t stream) {
  const float* emb = (const float*)d_in[0];
  const float* W1 = (const float*)d_in[1];
  const float* b1 = (const float*)d_in[2];
  const float* W2 = (const float*)d_in[3];
  const float* b2 = (const float*)d_in[4];
  float* out = (float*)d_out;
  hipLaunchKernelGGL(k12_fused, dim3(4, 256), dim3(256), 0, stream, emb, W1, b1, W2);
  hipLaunchKernelGGL(k_tail1, dim3(32), dim3(256), 0, stream, b2);
  hipLaunchKernelGGL(k_tail2, dim3(1), dim3(256), 0, stream, out);
}